// Round 7
// baseline (1541.546 us; speedup 1.0000x reference)
//
#include <hip/hip_runtime.h>
#include <math.h>

#define LEAKY 0.2f
#define BN_EPS 1e-5f

typedef unsigned short u16;
typedef __bf16 bf16x8 __attribute__((ext_vector_type(8)));
typedef float f32x4 __attribute__((ext_vector_type(4)));
typedef u16 ushort8 __attribute__((ext_vector_type(8)));

__device__ __forceinline__ u16 f2bf(float x){
    unsigned u = __float_as_uint(x);
    u += 0x7FFFu + ((u >> 16) & 1u);          // RNE (finite data, no NaN)
    return (u16)(u >> 16);
}
__device__ __forceinline__ float bf2f(u16 b){ return __uint_as_float(((unsigned)b) << 16); }

// monotone float<->uint encoding for atomicMax on floats
__device__ __forceinline__ unsigned enc_ord(float x){
    unsigned u = __float_as_uint(x);
    return (u & 0x80000000u) ? ~u : (u | 0x80000000u);
}
__device__ __forceinline__ float dec_ord(unsigned u){
    unsigned b = (u & 0x80000000u) ? (u ^ 0x80000000u) : ~u;
    return __uint_as_float(b);
}

// ---------------- encoder ----------------

__global__ __launch_bounds__(256) void k_encoder(const float* __restrict__ x,
        const float* __restrict__ W, const float* __restrict__ b,
        float* __restrict__ z, int N){
    int gid = blockIdx.x*256 + threadIdx.x;
    int n = gid >> 6, j = gid & 63;
    if (n >= N) return;
    float acc = b[j];
    #pragma unroll
    for (int k=0;k<7;k++) acc += x[n*7+k]*W[k*64+j];
    z[(size_t)n*64+j] = acc;
}

// pack W[K][M] fp32 -> hi/lo bf16 in MFMA B-fragment layout
template<int K, int M>
__global__ __launch_bounds__(256) void k_pack_w(const float* __restrict__ W,
        u16* __restrict__ hi, u16* __restrict__ lo){
    int idx = blockIdx.x*256 + threadIdx.x;
    if (idx >= K*M) return;
    int e = idx & 7, l16 = (idx >> 3) & 3, rest = idx >> 5;
    int n = rest % M, t = rest / M;
    int k = t*32 + l16*8 + e;
    float w = W[(size_t)k*M + n];
    u16 hb = f2bf(w);
    hi[idx] = hb;
    lo[idx] = f2bf(w - bf2f(hb));
}

// BN coefs: scale = gamma*rsqrt(var+eps); shift = beta - mu*scale
__global__ void k_bn_coef(const float* __restrict__ cs, const float* __restrict__ cq,
        const float* __restrict__ g, const float* __restrict__ be,
        float* __restrict__ scale, float* __restrict__ shift, float invN){
    int j = threadIdx.x;   // 128
    float mu = cs[j]*invN;
    float var = cq[j]*invN - mu*mu;
    float s = g[j]*rsqrtf(var + BN_EPS);
    scale[j] = s; shift[j] = be[j] - mu*s;
}

// split-bf16 MFMA GEMM, fused input-BN+ReLU (staging), fused attention-logit
// epilogue with global per-head logit max (mh); writes h as bf16.
template<int K, int M, int RW, int CW, int WR, int WC, int H, bool BNIN>
__global__ __launch_bounds__(256) void k_gemm(const float* __restrict__ z,
        const u16* __restrict__ Whi, const u16* __restrict__ Wlo,
        const float* __restrict__ bnscale, const float* __restrict__ bnshift,
        const float* __restrict__ a_src, const float* __restrict__ a_dst,
        u16* __restrict__ hout, float* __restrict__ al_s, float* __restrict__ al_d,
        unsigned* __restrict__ mh, int N)
{
    static_assert(RW*CW == 4 && RW*WR*16 == 64 && CW*WC*16 == M, "tile config");
    constexpr int KS = K/32;
    constexpr int KG = K/8;
    __shared__ __align__(16) u16 Ahi[64*K];
    __shared__ __align__(16) u16 Alo[64*K];
    const int brow = blockIdx.x*64;
    const int tid = threadIdx.x;

    // stage A-tile: fp32 -> (BN+ReLU) -> hi/lo bf16 fragments
    for (int u = tid; u < 64*KG; u += 256){
        int row = u / KG, kg = u % KG;
        int gr = brow + row;
        float v[8];
        if (gr < N){
            const float4* p = (const float4*)(z + (size_t)gr*K + kg*8);
            float4 a = p[0], bq = p[1];
            v[0]=a.x; v[1]=a.y; v[2]=a.z; v[3]=a.w;
            v[4]=bq.x; v[5]=bq.y; v[6]=bq.z; v[7]=bq.w;
            if (BNIN){
                const float4* sc = (const float4*)(bnscale + kg*8);
                const float4* sh = (const float4*)(bnshift + kg*8);
                float4 s0=sc[0], s1=sc[1], t0=sh[0], t1=sh[1];
                v[0]=fmaxf(fmaf(v[0],s0.x,t0.x),0.f);
                v[1]=fmaxf(fmaf(v[1],s0.y,t0.y),0.f);
                v[2]=fmaxf(fmaf(v[2],s0.z,t0.z),0.f);
                v[3]=fmaxf(fmaf(v[3],s0.w,t0.w),0.f);
                v[4]=fmaxf(fmaf(v[4],s1.x,t1.x),0.f);
                v[5]=fmaxf(fmaf(v[5],s1.y,t1.y),0.f);
                v[6]=fmaxf(fmaf(v[6],s1.z,t1.z),0.f);
                v[7]=fmaxf(fmaf(v[7],s1.w,t1.w),0.f);
            }
        } else {
            #pragma unroll
            for (int e=0;e<8;e++) v[e]=0.f;
        }
        ushort8 h8, l8;
        #pragma unroll
        for (int e=0;e<8;e++){
            u16 hb = f2bf(v[e]);
            h8[e] = hb;
            l8[e] = f2bf(v[e] - bf2f(hb));
        }
        int rb = row >> 4, t = kg >> 2, lg = kg & 3;
        int base = (((rb*KS + t)*64) + (row & 15) + 16*lg)*8;
        *(ushort8*)&Ahi[base] = h8;
        *(ushort8*)&Alo[base] = l8;
    }
    __syncthreads();

    const int wave = tid >> 6, lane = tid & 63;
    const int wrow = wave / CW, wcol = wave % CW;
    const int l15 = lane & 15, l16 = lane >> 4;

    f32x4 acc[WR][WC];
    #pragma unroll
    for (int r=0;r<WR;r++)
        #pragma unroll
        for (int c=0;c<WC;c++) acc[r][c] = (f32x4){0.f,0.f,0.f,0.f};

    #pragma unroll
    for (int t = 0; t < KS; ++t){
        bf16x8 ah[WR], al[WR];
        #pragma unroll
        for (int r=0;r<WR;r++){
            int rb = wrow*WR + r;
            int off = ((rb*KS + t)*64 + lane)*8;
            ah[r] = *(const bf16x8*)&Ahi[off];
            al[r] = *(const bf16x8*)&Alo[off];
        }
        bf16x8 bh[WC], bl[WC];
        #pragma unroll
        for (int c=0;c<WC;c++){
            int n = (wcol*WC + c)*16 + l15;
            size_t off = ((size_t)(t*M + n)*4 + (size_t)l16)*8;
            bh[c] = *(const bf16x8*)&Whi[off];
            bl[c] = *(const bf16x8*)&Wlo[off];
        }
        #pragma unroll
        for (int r=0;r<WR;r++)
            #pragma unroll
            for (int c=0;c<WC;c++){
                acc[r][c] = __builtin_amdgcn_mfma_f32_16x16x32_bf16(al[r], bh[c], acc[r][c], 0,0,0);
                acc[r][c] = __builtin_amdgcn_mfma_f32_16x16x32_bf16(ah[r], bl[c], acc[r][c], 0,0,0);
                acc[r][c] = __builtin_amdgcn_mfma_f32_16x16x32_bf16(ah[r], bh[c], acc[r][c], 0,0,0);
            }
    }

    // fused attention-logit epilogue + per-head global max of al_s
    float as_[WC], ad_[WC];
    #pragma unroll
    for (int c=0;c<WC;c++){
        int colg = (wcol*WC + c)*16 + l15;
        as_[c] = a_src[colg]; ad_[c] = a_dst[colg];
    }
    float wm0 = -1e30f, wm1 = -1e30f;
    #pragma unroll
    for (int r=0;r<WR;r++){
        #pragma unroll
        for (int q=0;q<4;q++){
            int rowg = brow + (wrow*WR + r)*16 + l16*4 + q;
            float s0=0.f,d0=0.f,s1=0.f,d1=0.f;
            #pragma unroll
            for (int c=0;c<WC;c++){
                float av = acc[r][c][q];
                if (H==1 || c < WC/2){ s0 += av*as_[c]; d0 += av*ad_[c]; }
                else                 { s1 += av*as_[c]; d1 += av*ad_[c]; }
            }
            #pragma unroll
            for (int off=1; off<16; off<<=1){
                s0 += __shfl_xor(s0, off, 64); d0 += __shfl_xor(d0, off, 64);
                if (H==4){ s1 += __shfl_xor(s1, off, 64); d1 += __shfl_xor(d1, off, 64); }
            }
            wm0 = fmaxf(wm0, s0);
            if (H==4) wm1 = fmaxf(wm1, s1);
            if (l15 == 0 && rowg < N){
                if (H==4){
                    al_s[(size_t)rowg*4 + wcol*2]     = s0;
                    al_s[(size_t)rowg*4 + wcol*2 + 1] = s1;
                    al_d[(size_t)rowg*4 + wcol*2]     = d0;
                    al_d[(size_t)rowg*4 + wcol*2 + 1] = d1;
                } else {
                    al_s[rowg] = s0; al_d[rowg] = d0;
                }
            }
        }
    }
    wm0 = fmaxf(wm0, __shfl_xor(wm0, 16, 64));
    wm0 = fmaxf(wm0, __shfl_xor(wm0, 32, 64));
    if (H==4){
        wm1 = fmaxf(wm1, __shfl_xor(wm1, 16, 64));
        wm1 = fmaxf(wm1, __shfl_xor(wm1, 32, 64));
    }
    if (lane == 0){
        atomicMax(mh + (H==4 ? wcol*2 : 0), enc_ord(wm0));
        if (H==4) atomicMax(mh + wcol*2 + 1, enc_ord(wm1));
    }

    // h write (bf16)
    #pragma unroll
    for (int r=0;r<WR;r++)
        #pragma unroll
        for (int c=0;c<WC;c++){
            int colg = (wcol*WC + c)*16 + l15;
            #pragma unroll
            for (int q=0;q<4;q++){
                int rowg = brow + (wrow*WR + r)*16 + l16*4 + q;
                if (rowg < N) hout[(size_t)rowg*M + colg] = f2bf(acc[r][c][q]);
            }
        }
}

// ---------------- CSR build (once per call) ----------------

__global__ __launch_bounds__(256) void k_deg(const int* __restrict__ ei, int E,
        int* __restrict__ deg){
    int e = blockIdx.x*256 + threadIdx.x;
    if (e < E) atomicAdd(deg + ei[E+e], 1);
}

__device__ __forceinline__ int wave_scan(int v, int lane){
    #pragma unroll
    for (int off=1; off<64; off<<=1){
        int t = __shfl_up(v, off, 64);
        if (lane >= off) v += t;
    }
    return v;
}

__global__ __launch_bounds__(1024) void k_scan1(const int* __restrict__ deg,
        int* __restrict__ excl, int* __restrict__ bsum, int N){
    __shared__ int ws[16];
    int i = blockIdx.x*1024 + threadIdx.x;
    int lane = threadIdx.x & 63, wid = threadIdx.x >> 6;
    int v = (i < N) ? deg[i] : 0;
    int inc = wave_scan(v, lane);
    if (lane == 63) ws[wid] = inc;
    __syncthreads();
    if (wid == 0){
        int wv = (lane < 16) ? ws[lane] : 0;
        int winc = wave_scan(wv, lane);
        if (lane < 16) ws[lane] = winc - wv;
    }
    __syncthreads();
    int off = ws[wid];
    if (i < N) excl[i] = off + inc - v;
    if (threadIdx.x == 1023) bsum[blockIdx.x] = off + inc;
}

__global__ void k_scan2(int* __restrict__ bsum, int nb){
    if (threadIdx.x == 0 && blockIdx.x == 0){
        int c = 0;
        for (int i = 0; i < nb; i++){ int t = bsum[i]; bsum[i] = c; c += t; }
    }
}

__global__ __launch_bounds__(256) void k_scan3(const int* __restrict__ excl,
        const int* __restrict__ bsum, int* __restrict__ rowptr,
        int* __restrict__ cursor, int N, int E){
    int i = blockIdx.x*256 + threadIdx.x;
    if (i < N){
        int r = excl[i] + bsum[i >> 10];
        rowptr[i] = r; cursor[i] = r;
    } else if (i == N){
        rowptr[N] = E;
    }
}

__global__ __launch_bounds__(256) void k_bucket(const int* __restrict__ ei, int E,
        int* __restrict__ cursor, int* __restrict__ csr){
    int e = blockIdx.x*256 + threadIdx.x;
    if (e >= E) return;
    int pos = atomicAdd(cursor + ei[E+e], 1);
    csr[pos] = ei[e];
}

// ---------------- GAT aggregation: wave per dst (grid-stride), bf16 gathers,
// fixed-upper-bound softmax (no online rescale -> independent edge bodies),
// quad ping-pong prefetch, fused BN stats, optional fused decoder ----------------

template<int H, int C, bool STATS, bool DECODE>
__global__ __launch_bounds__(256) void k_gat_agg(
        const int* __restrict__ rowptr, const int* __restrict__ csr_src,
        const float* __restrict__ al_s, const float* __restrict__ al_d,
        const unsigned* __restrict__ mh,
        const u16* __restrict__ hfeat, const float* __restrict__ b,
        float* __restrict__ z, float* __restrict__ cs, float* __restrict__ cq,
        const float* __restrict__ decW, const float* __restrict__ decb,
        float* __restrict__ out, int N, int totWaves)
{
    constexpr int M = H*C;
    constexpr int EL = M/64;                  // 2 (M=128) or 1 (M=64)
    const int lane = threadIdx.x & 63;
    const int j = EL*lane;
    const int h = j / C;
    const int gw = blockIdx.x*4 + (threadIdx.x >> 6);

    const float bj0 = b[j];
    const float bj1 = (EL==2) ? b[j+1] : 0.f;
    const float mhf = dec_ord(mh[h]);         // global per-head max of al_s
    float w0=0,w1=0,w2=0,w3=0;
    if (DECODE){ w0=decW[lane*4]; w1=decW[lane*4+1]; w2=decW[lane*4+2]; w3=decW[lane*4+3]; }
    float ls0=0.f, ls1=0.f, lq0=0.f, lq1=0.f;

    for (int dst = gw; dst < N; dst += totWaves){
        int p0 = rowptr[dst], p1 = rowptr[dst+1];     // issue early
        float ald = al_d[(size_t)dst*H + h];
        // mb >= max over segment (incl. self); clamp so s >= e^-40 stays normal
        float t = mhf + ald;
        float mb = t > 0.f ? t : LEAKY*t;
        float v0 = al_s[(size_t)dst*H + h] + ald;
        v0 = v0 > 0.f ? v0 : LEAKY*v0;
        mb = fminf(mb, v0 + 40.f);

        float ex0 = __expf(v0 - mb);
        float s = ex0;
        float acc0, acc1 = 0.f;
        if (EL==2){
            unsigned hv = *(const unsigned*)(hfeat + (size_t)dst*M + j);
            acc0 = bf2f((u16)hv)*ex0; acc1 = bf2f((u16)(hv>>16))*ex0;
        } else {
            acc0 = bf2f(hfeat[(size_t)dst*M + j])*ex0;
        }

        auto ld = [&](int idx, unsigned& hv, float& vs){
            if (idx < p1){
                int src = csr_src[idx];
                vs = al_s[(size_t)src*H + h];
                if (EL==2) hv = *(const unsigned*)(hfeat + (size_t)src*M + j);
                else       hv = (unsigned)hfeat[(size_t)src*M + j];
            }
        };
        auto proc = [&](unsigned hv, float vs){
            float vv = vs + ald;
            vv = vv > 0.f ? vv : LEAKY*vv;
            float ex = __expf(vv - mb);
            s += ex;
            acc0 = fmaf(bf2f((u16)hv), ex, acc0);
            if (EL==2) acc1 = fmaf(bf2f((u16)(hv>>16)), ex, acc1);
        };

        unsigned hA0=0,hA1=0,hA2=0,hA3=0, hB0=0,hB1=0,hB2=0,hB3=0;
        float vA0=0,vA1=0,vA2=0,vA3=0, vB0=0,vB1=0,vB2=0,vB3=0;
        int p = p0;
        ld(p, hA0, vA0); ld(p+1, hA1, vA1); ld(p+2, hA2, vA2); ld(p+3, hA3, vA3);
        while (p < p1){
            ld(p+4, hB0, vB0); ld(p+5, hB1, vB1); ld(p+6, hB2, vB2); ld(p+7, hB3, vB3);
            proc(hA0, vA0);
            if (p+1 < p1) proc(hA1, vA1);
            if (p+2 < p1) proc(hA2, vA2);
            if (p+3 < p1) proc(hA3, vA3);
            p += 4;
            if (p >= p1) break;
            ld(p+4, hA0, vA0); ld(p+5, hA1, vA1); ld(p+6, hA2, vA2); ld(p+7, hA3, vA3);
            proc(hB0, vB0);
            if (p+1 < p1) proc(hB1, vB1);
            if (p+2 < p1) proc(hB2, vB2);
            if (p+3 < p1) proc(hB3, vB3);
            p += 4;
        }

        float inv = 1.f/s;                     // s >= e^-40 > 0 (self-loop)
        float o0 = acc0*inv + bj0;
        float o1 = (EL==2) ? acc1*inv + bj1 : 0.f;
        if (STATS){ ls0+=o0; lq0+=o0*o0; ls1+=o1; lq1+=o1*o1; }
        if (!DECODE){
            if (EL==2) *(float2*)(z + (size_t)dst*M + j) = make_float2(o0,o1);
            else       z[(size_t)dst*M + j] = o0;
        } else {
            float a0=o0*w0, a1=o0*w1, a2=o0*w2, a3=o0*w3;
            #pragma unroll
            for (int off=32; off; off>>=1){
                a0 += __shfl_xor(a0, off, 64);
                a1 += __shfl_xor(a1, off, 64);
                a2 += __shfl_xor(a2, off, 64);
                a3 += __shfl_xor(a3, off, 64);
            }
            if (lane == 0){
                float4 o = make_float4(a0+decb[0], a1+decb[1], a2+decb[2], a3+decb[3]);
                *(float4*)(out + (size_t)dst*4) = o;
            }
        }
    }
    if (STATS){
        __shared__ float sls[128], slq[128];
        if (threadIdx.x < 128){ sls[threadIdx.x]=0.f; slq[threadIdx.x]=0.f; }
        __syncthreads();
        atomicAdd(&sls[j], ls0);  atomicAdd(&slq[j], lq0);
        if (EL==2){ atomicAdd(&sls[j+1], ls1); atomicAdd(&slq[j+1], lq1); }
        __syncthreads();
        if (threadIdx.x < 128){
            atomicAdd(cs + threadIdx.x, sls[threadIdx.x]);
            atomicAdd(cq + threadIdx.x, slq[threadIdx.x]);
        }
    }
}

extern "C" void kernel_launch(void* const* d_in, const int* in_sizes, int n_in,
                              void* d_out, int out_size, void* d_ws, size_t ws_size,
                              hipStream_t stream){
    const float* x      = (const float*)d_in[0];
    const int*   ei     = (const int*)  d_in[1];
    const float* enc_W  = (const float*)d_in[2];
    const float* enc_b  = (const float*)d_in[3];
    const float* in_W   = (const float*)d_in[4];
    const float* in_as  = (const float*)d_in[5];
    const float* in_ad  = (const float*)d_in[6];
    const float* in_b   = (const float*)d_in[7];
    const float* hid_W  = (const float*)d_in[8];
    const float* hid_as = (const float*)d_in[9];
    const float* hid_ad = (const float*)d_in[10];
    const float* hid_b  = (const float*)d_in[11];
    const float* bn_g   = (const float*)d_in[12];
    const float* bn_b   = (const float*)d_in[13];
    const float* out_W  = (const float*)d_in[14];
    const float* out_as = (const float*)d_in[15];
    const float* out_ad = (const float*)d_in[16];
    const float* out_b  = (const float*)d_in[17];
    const float* dec_W  = (const float*)d_in[18];
    const float* dec_b  = (const float*)d_in[19];

    const int N = in_sizes[0] / 7;
    const int E = in_sizes[1] / 2;
    const int NB = (N + 1023) / 1024;
    const int NT = (N + 63) / 64;
    const int AGG_BLOCKS = 2048, TOT_WAVES = AGG_BLOCKS*4;

    // workspace layout:
    float*    bufZ   = (float*)d_ws;                  // [N,128] fp32 activations
    float*    al_s   = bufZ + (size_t)N*128;          // [N,4]
    float*    al_d   = al_s + (size_t)N*4;            // [N,4]
    float*    cs     = al_d + (size_t)N*4;            // [128]
    float*    cq     = cs + 128;                      // [128]
    unsigned* mh     = (unsigned*)(cq + 128);         // [8] per-head logit max (enc)
    float*    scale  = (float*)(mh + 8);              // [128]
    float*    shift  = scale + 128;                   // [128]
    int*      deg    = (int*)(shift + 128);           // [N]
    int*      excl   = deg + N;                       // [N]
    int*      rowptr = excl + N;                      // [N+1]
    int*      cursor = rowptr + (N+1);                // [N]
    int*      bsum   = cursor + N;                    // [NB]
    int*      csr    = bsum + NB;                     // [E]
    u16*      hb     = (u16*)(((uintptr_t)(csr + E) + 15) & ~(uintptr_t)15); // [N,128] bf16
    u16*      wk     = hb + (size_t)N*128;
    u16* wk_in_hi  = wk;                    u16* wk_in_lo  = wk_in_hi  + 64*128;
    u16* wk_h0_hi  = wk_in_lo  + 64*128;    u16* wk_h0_lo  = wk_h0_hi  + 128*128;
    u16* wk_h1_hi  = wk_h0_lo  + 128*128;   u16* wk_h1_lo  = wk_h1_hi  + 128*128;
    u16* wk_out_hi = wk_h1_lo  + 128*128;   u16* wk_out_lo = wk_out_hi + 128*64;

    const size_t STATS_BYTES = (128 + 128 + 8) * 4;   // cs|cq|mh contiguous

    // ---- pack weights ----
    k_pack_w<64,128><<<(64*128+255)/256, 256, 0, stream>>>(in_W, wk_in_hi, wk_in_lo);
    k_pack_w<128,128><<<(128*128+255)/256, 256, 0, stream>>>(hid_W, wk_h0_hi, wk_h0_lo);
    k_pack_w<128,128><<<(128*128+255)/256, 256, 0, stream>>>(hid_W + 128*128, wk_h1_hi, wk_h1_lo);
    k_pack_w<128,64><<<(128*64+255)/256, 256, 0, stream>>>(out_W, wk_out_hi, wk_out_lo);

    // ---- CSR build ----
    hipMemsetAsync(deg, 0, (size_t)N*sizeof(int), stream);
    k_deg   <<<(E+255)/256, 256, 0, stream>>>(ei, E, deg);
    k_scan1 <<<NB, 1024, 0, stream>>>(deg, excl, bsum, N);
    k_scan2 <<<1, 64, 0, stream>>>(bsum, NB);
    k_scan3 <<<(N+1+255)/256, 256, 0, stream>>>(excl, bsum, rowptr, cursor, N, E);
    k_bucket<<<(E+255)/256, 256, 0, stream>>>(ei, E, cursor, csr);

    // ---- encoder ----
    k_encoder<<<(N*64+255)/256, 256, 0, stream>>>(x, enc_W, enc_b, bufZ, N);

    const float invN = 1.f/(float)N;

    // ---- GAT layer 1 (K=64, no input BN) ----
    hipMemsetAsync(cs, 0, STATS_BYTES, stream);
    k_gemm<64,128,2,2,2,4,4,false><<<NT, 256, 0, stream>>>(bufZ, wk_in_hi, wk_in_lo,
            nullptr, nullptr, in_as, in_ad, hb, al_s, al_d, mh, N);
    k_gat_agg<4,32,true,false><<<AGG_BLOCKS, 256, 0, stream>>>(rowptr, csr, al_s, al_d, mh,
            hb, in_b, bufZ, cs, cq, nullptr, nullptr, nullptr, N, TOT_WAVES);
    k_bn_coef<<<1, 128, 0, stream>>>(cs, cq, bn_g, bn_b, scale, shift, invN);

    // ---- hidden GAT layers (input BN+ReLU fused into GEMM staging) ----
    for (int i = 0; i < 2; i++){
        const u16* whi = i ? wk_h1_hi : wk_h0_hi;
        const u16* wlo = i ? wk_h1_lo : wk_h0_lo;
        hipMemsetAsync(cs, 0, STATS_BYTES, stream);
        k_gemm<128,128,2,2,2,4,4,true><<<NT, 256, 0, stream>>>(bufZ, whi, wlo,
                scale, shift, hid_as + (size_t)i*128, hid_ad + (size_t)i*128,
                hb, al_s, al_d, mh, N);
        k_gat_agg<4,32,true,false><<<AGG_BLOCKS, 256, 0, stream>>>(rowptr, csr, al_s, al_d, mh,
                hb, hid_b + (size_t)i*128, bufZ, cs, cq, nullptr, nullptr, nullptr, N, TOT_WAVES);
        k_bn_coef<<<1, 128, 0, stream>>>(cs, cq, bn_g + (i+1)*128, bn_b + (i+1)*128, scale, shift, invN);
    }

    // ---- out GAT layer (K=128 -> 1x64) + fused decoder ----
    hipMemsetAsync(cs, 0, STATS_BYTES, stream);
    k_gemm<128,64,4,1,1,4,1,true><<<NT, 256, 0, stream>>>(bufZ, wk_out_hi, wk_out_lo,
            scale, shift, out_as, out_ad, hb, al_s, al_d, mh, N);
    k_gat_agg<1,64,false,true><<<AGG_BLOCKS, 256, 0, stream>>>(rowptr, csr, al_s, al_d, mh,
            hb, out_b, nullptr, nullptr, nullptr, dec_W, dec_b, (float*)d_out, N, TOT_WAVES);
}

// Round 8
// 979.349 us; speedup vs baseline: 1.5741x; 1.5741x over previous
//
#include <hip/hip_runtime.h>
#include <math.h>

#define LEAKY 0.2f
#define BN_EPS 1e-5f

typedef unsigned short u16;
typedef __bf16 bf16x8 __attribute__((ext_vector_type(8)));
typedef float f32x4 __attribute__((ext_vector_type(4)));
typedef u16 ushort8 __attribute__((ext_vector_type(8)));

__device__ __forceinline__ u16 f2bf(float x){
    unsigned u = __float_as_uint(x);
    u += 0x7FFFu + ((u >> 16) & 1u);          // RNE (finite data, no NaN)
    return (u16)(u >> 16);
}
__device__ __forceinline__ float bf2f(u16 b){ return __uint_as_float(((unsigned)b) << 16); }

// ---------------- encoder ----------------

__global__ __launch_bounds__(256) void k_encoder(const float* __restrict__ x,
        const float* __restrict__ W, const float* __restrict__ b,
        float* __restrict__ z, int N){
    int gid = blockIdx.x*256 + threadIdx.x;
    int n = gid >> 6, j = gid & 63;
    if (n >= N) return;
    float acc = b[j];
    #pragma unroll
    for (int k=0;k<7;k++) acc += x[n*7+k]*W[k*64+j];
    z[(size_t)n*64+j] = acc;
}

// pack W[K][M] fp32 -> hi/lo bf16 in MFMA B-fragment layout
template<int K, int M>
__global__ __launch_bounds__(256) void k_pack_w(const float* __restrict__ W,
        u16* __restrict__ hi, u16* __restrict__ lo){
    int idx = blockIdx.x*256 + threadIdx.x;
    if (idx >= K*M) return;
    int e = idx & 7, l16 = (idx >> 3) & 3, rest = idx >> 5;
    int n = rest % M, t = rest / M;
    int k = t*32 + l16*8 + e;
    float w = W[(size_t)k*M + n];
    u16 hb = f2bf(w);
    hi[idx] = hb;
    lo[idx] = f2bf(w - bf2f(hb));
}

// BN coefs: scale = gamma*rsqrt(var+eps); shift = beta - mu*scale
__global__ void k_bn_coef(const float* __restrict__ cs, const float* __restrict__ cq,
        const float* __restrict__ g, const float* __restrict__ be,
        float* __restrict__ scale, float* __restrict__ shift, float invN){
    int j = threadIdx.x;   // 128
    float mu = cs[j]*invN;
    float var = cq[j]*invN - mu*mu;
    float s = g[j]*rsqrtf(var + BN_EPS);
    scale[j] = s; shift[j] = be[j] - mu*s;
}

// ---------------- per-head global max of al_s (two-pass, no atomics) ----------------

// pass 1: 64 blocks, grid-stride; head of element i is i%H, constant per thread
template<int H>
__global__ __launch_bounds__(256) void k_mh1(const float* __restrict__ al,
        float* __restrict__ pm, int total){
    int t = threadIdx.x;
    float m = -1e30f;
    for (int i = blockIdx.x*256 + t; i < total; i += 64*256)
        m = fmaxf(m, al[i]);
    #pragma unroll
    for (int off = H; off < 64; off <<= 1)
        m = fmaxf(m, __shfl_xor(m, off, 64));
    __shared__ float ws[16];
    int lane = t & 63, wid = t >> 6;
    if (lane < H) ws[wid*H + lane] = m;
    __syncthreads();
    if (t < H){
        float mm = ws[t];
        #pragma unroll
        for (int w = 1; w < 4; w++) mm = fmaxf(mm, ws[w*H + t]);
        pm[blockIdx.x*H + t] = mm;
    }
}

// pass 2: one wave reduces 64*H partials -> mh[H] (plain float)
template<int H>
__global__ void k_mh2(const float* __restrict__ pm, float* __restrict__ mh){
    int t = threadIdx.x;   // 64 threads
    float m = -1e30f;
    #pragma unroll
    for (int k = 0; k < H; k++) m = fmaxf(m, pm[t + k*64]);
    #pragma unroll
    for (int off = H; off < 64; off <<= 1)
        m = fmaxf(m, __shfl_xor(m, off, 64));
    if (t < H) mh[t] = m;
}

// split-bf16 MFMA GEMM, fused input-BN+ReLU (staging), fused attention-logit
// epilogue; writes h as bf16. (No atomics anywhere — round-5 form.)
template<int K, int M, int RW, int CW, int WR, int WC, int H, bool BNIN>
__global__ __launch_bounds__(256) void k_gemm(const float* __restrict__ z,
        const u16* __restrict__ Whi, const u16* __restrict__ Wlo,
        const float* __restrict__ bnscale, const float* __restrict__ bnshift,
        const float* __restrict__ a_src, const float* __restrict__ a_dst,
        u16* __restrict__ hout, float* __restrict__ al_s, float* __restrict__ al_d,
        int N)
{
    static_assert(RW*CW == 4 && RW*WR*16 == 64 && CW*WC*16 == M, "tile config");
    constexpr int KS = K/32;
    constexpr int KG = K/8;
    __shared__ __align__(16) u16 Ahi[64*K];
    __shared__ __align__(16) u16 Alo[64*K];
    const int brow = blockIdx.x*64;
    const int tid = threadIdx.x;

    // stage A-tile: fp32 -> (BN+ReLU) -> hi/lo bf16 fragments
    for (int u = tid; u < 64*KG; u += 256){
        int row = u / KG, kg = u % KG;
        int gr = brow + row;
        float v[8];
        if (gr < N){
            const float4* p = (const float4*)(z + (size_t)gr*K + kg*8);
            float4 a = p[0], bq = p[1];
            v[0]=a.x; v[1]=a.y; v[2]=a.z; v[3]=a.w;
            v[4]=bq.x; v[5]=bq.y; v[6]=bq.z; v[7]=bq.w;
            if (BNIN){
                const float4* sc = (const float4*)(bnscale + kg*8);
                const float4* sh = (const float4*)(bnshift + kg*8);
                float4 s0=sc[0], s1=sc[1], t0=sh[0], t1=sh[1];
                v[0]=fmaxf(fmaf(v[0],s0.x,t0.x),0.f);
                v[1]=fmaxf(fmaf(v[1],s0.y,t0.y),0.f);
                v[2]=fmaxf(fmaf(v[2],s0.z,t0.z),0.f);
                v[3]=fmaxf(fmaf(v[3],s0.w,t0.w),0.f);
                v[4]=fmaxf(fmaf(v[4],s1.x,t1.x),0.f);
                v[5]=fmaxf(fmaf(v[5],s1.y,t1.y),0.f);
                v[6]=fmaxf(fmaf(v[6],s1.z,t1.z),0.f);
                v[7]=fmaxf(fmaf(v[7],s1.w,t1.w),0.f);
            }
        } else {
            #pragma unroll
            for (int e=0;e<8;e++) v[e]=0.f;
        }
        ushort8 h8, l8;
        #pragma unroll
        for (int e=0;e<8;e++){
            u16 hb = f2bf(v[e]);
            h8[e] = hb;
            l8[e] = f2bf(v[e] - bf2f(hb));
        }
        int rb = row >> 4, t = kg >> 2, lg = kg & 3;
        int base = (((rb*KS + t)*64) + (row & 15) + 16*lg)*8;
        *(ushort8*)&Ahi[base] = h8;
        *(ushort8*)&Alo[base] = l8;
    }
    __syncthreads();

    const int wave = tid >> 6, lane = tid & 63;
    const int wrow = wave / CW, wcol = wave % CW;
    const int l15 = lane & 15, l16 = lane >> 4;

    f32x4 acc[WR][WC];
    #pragma unroll
    for (int r=0;r<WR;r++)
        #pragma unroll
        for (int c=0;c<WC;c++) acc[r][c] = (f32x4){0.f,0.f,0.f,0.f};

    #pragma unroll
    for (int t = 0; t < KS; ++t){
        bf16x8 ah[WR], al[WR];
        #pragma unroll
        for (int r=0;r<WR;r++){
            int rb = wrow*WR + r;
            int off = ((rb*KS + t)*64 + lane)*8;
            ah[r] = *(const bf16x8*)&Ahi[off];
            al[r] = *(const bf16x8*)&Alo[off];
        }
        bf16x8 bh[WC], bl[WC];
        #pragma unroll
        for (int c=0;c<WC;c++){
            int n = (wcol*WC + c)*16 + l15;
            size_t off = ((size_t)(t*M + n)*4 + (size_t)l16)*8;
            bh[c] = *(const bf16x8*)&Whi[off];
            bl[c] = *(const bf16x8*)&Wlo[off];
        }
        #pragma unroll
        for (int r=0;r<WR;r++)
            #pragma unroll
            for (int c=0;c<WC;c++){
                acc[r][c] = __builtin_amdgcn_mfma_f32_16x16x32_bf16(al[r], bh[c], acc[r][c], 0,0,0);
                acc[r][c] = __builtin_amdgcn_mfma_f32_16x16x32_bf16(ah[r], bl[c], acc[r][c], 0,0,0);
                acc[r][c] = __builtin_amdgcn_mfma_f32_16x16x32_bf16(ah[r], bh[c], acc[r][c], 0,0,0);
            }
    }

    // fused attention-logit epilogue
    float as_[WC], ad_[WC];
    #pragma unroll
    for (int c=0;c<WC;c++){
        int colg = (wcol*WC + c)*16 + l15;
        as_[c] = a_src[colg]; ad_[c] = a_dst[colg];
    }
    #pragma unroll
    for (int r=0;r<WR;r++){
        #pragma unroll
        for (int q=0;q<4;q++){
            int rowg = brow + (wrow*WR + r)*16 + l16*4 + q;
            float s0=0.f,d0=0.f,s1=0.f,d1=0.f;
            #pragma unroll
            for (int c=0;c<WC;c++){
                float av = acc[r][c][q];
                if (H==1 || c < WC/2){ s0 += av*as_[c]; d0 += av*ad_[c]; }
                else                 { s1 += av*as_[c]; d1 += av*ad_[c]; }
            }
            #pragma unroll
            for (int off=1; off<16; off<<=1){
                s0 += __shfl_xor(s0, off, 64); d0 += __shfl_xor(d0, off, 64);
                if (H==4){ s1 += __shfl_xor(s1, off, 64); d1 += __shfl_xor(d1, off, 64); }
            }
            if (l15 == 0 && rowg < N){
                if (H==4){
                    al_s[(size_t)rowg*4 + wcol*2]     = s0;
                    al_s[(size_t)rowg*4 + wcol*2 + 1] = s1;
                    al_d[(size_t)rowg*4 + wcol*2]     = d0;
                    al_d[(size_t)rowg*4 + wcol*2 + 1] = d1;
                } else {
                    al_s[rowg] = s0; al_d[rowg] = d0;
                }
            }
        }
    }

    // h write (bf16)
    #pragma unroll
    for (int r=0;r<WR;r++)
        #pragma unroll
        for (int c=0;c<WC;c++){
            int colg = (wcol*WC + c)*16 + l15;
            #pragma unroll
            for (int q=0;q<4;q++){
                int rowg = brow + (wrow*WR + r)*16 + l16*4 + q;
                if (rowg < N) hout[(size_t)rowg*M + colg] = f2bf(acc[r][c][q]);
            }
        }
}

// ---------------- CSR build (once per call) ----------------

__global__ __launch_bounds__(256) void k_deg(const int* __restrict__ ei, int E,
        int* __restrict__ deg){
    int e = blockIdx.x*256 + threadIdx.x;
    if (e < E) atomicAdd(deg + ei[E+e], 1);
}

__device__ __forceinline__ int wave_scan(int v, int lane){
    #pragma unroll
    for (int off=1; off<64; off<<=1){
        int t = __shfl_up(v, off, 64);
        if (lane >= off) v += t;
    }
    return v;
}

__global__ __launch_bounds__(1024) void k_scan1(const int* __restrict__ deg,
        int* __restrict__ excl, int* __restrict__ bsum, int N){
    __shared__ int ws[16];
    int i = blockIdx.x*1024 + threadIdx.x;
    int lane = threadIdx.x & 63, wid = threadIdx.x >> 6;
    int v = (i < N) ? deg[i] : 0;
    int inc = wave_scan(v, lane);
    if (lane == 63) ws[wid] = inc;
    __syncthreads();
    if (wid == 0){
        int wv = (lane < 16) ? ws[lane] : 0;
        int winc = wave_scan(wv, lane);
        if (lane < 16) ws[lane] = winc - wv;
    }
    __syncthreads();
    int off = ws[wid];
    if (i < N) excl[i] = off + inc - v;
    if (threadIdx.x == 1023) bsum[blockIdx.x] = off + inc;
}

__global__ void k_scan2(int* __restrict__ bsum, int nb){
    if (threadIdx.x == 0 && blockIdx.x == 0){
        int c = 0;
        for (int i = 0; i < nb; i++){ int t = bsum[i]; bsum[i] = c; c += t; }
    }
}

__global__ __launch_bounds__(256) void k_scan3(const int* __restrict__ excl,
        const int* __restrict__ bsum, int* __restrict__ rowptr,
        int* __restrict__ cursor, int N, int E){
    int i = blockIdx.x*256 + threadIdx.x;
    if (i < N){
        int r = excl[i] + bsum[i >> 10];
        rowptr[i] = r; cursor[i] = r;
    } else if (i == N){
        rowptr[N] = E;
    }
}

__global__ __launch_bounds__(256) void k_bucket(const int* __restrict__ ei, int E,
        int* __restrict__ cursor, int* __restrict__ csr){
    int e = blockIdx.x*256 + threadIdx.x;
    if (e >= E) return;
    int pos = atomicAdd(cursor + ei[E+e], 1);
    csr[pos] = ei[e];
}

// ---------------- GAT aggregation: wave per dst (grid-stride), bf16 gathers,
// fixed-upper-bound softmax (no online rescale -> independent edge bodies),
// quad ping-pong prefetch, fused BN stats, optional fused decoder ----------------

template<int H, int C, bool STATS, bool DECODE>
__global__ __launch_bounds__(256) void k_gat_agg(
        const int* __restrict__ rowptr, const int* __restrict__ csr_src,
        const float* __restrict__ al_s, const float* __restrict__ al_d,
        const float* __restrict__ mh,
        const u16* __restrict__ hfeat, const float* __restrict__ b,
        float* __restrict__ z, float* __restrict__ cs, float* __restrict__ cq,
        const float* __restrict__ decW, const float* __restrict__ decb,
        float* __restrict__ out, int N, int totWaves)
{
    constexpr int M = H*C;
    constexpr int EL = M/64;                  // 2 (M=128) or 1 (M=64)
    const int lane = threadIdx.x & 63;
    const int j = EL*lane;
    const int h = j / C;
    const int gw = blockIdx.x*4 + (threadIdx.x >> 6);

    const float bj0 = b[j];
    const float bj1 = (EL==2) ? b[j+1] : 0.f;
    const float mhf = mh[h];                  // global per-head max of al_s
    float w0=0,w1=0,w2=0,w3=0;
    if (DECODE){ w0=decW[lane*4]; w1=decW[lane*4+1]; w2=decW[lane*4+2]; w3=decW[lane*4+3]; }
    float ls0=0.f, ls1=0.f, lq0=0.f, lq1=0.f;

    for (int dst = gw; dst < N; dst += totWaves){
        int p0 = rowptr[dst], p1 = rowptr[dst+1];     // issue early
        float ald = al_d[(size_t)dst*H + h];
        // mb >= max over segment (incl. self); clamp so s >= e^-40 stays normal
        float t = mhf + ald;
        float mb = t > 0.f ? t : LEAKY*t;
        float v0 = al_s[(size_t)dst*H + h] + ald;
        v0 = v0 > 0.f ? v0 : LEAKY*v0;
        mb = fminf(mb, v0 + 40.f);

        float ex0 = __expf(v0 - mb);
        float s = ex0;
        float acc0, acc1 = 0.f;
        if (EL==2){
            unsigned hv = *(const unsigned*)(hfeat + (size_t)dst*M + j);
            acc0 = bf2f((u16)hv)*ex0; acc1 = bf2f((u16)(hv>>16))*ex0;
        } else {
            acc0 = bf2f(hfeat[(size_t)dst*M + j])*ex0;
        }

        auto ld = [&](int idx, unsigned& hv, float& vs){
            if (idx < p1){
                int src = csr_src[idx];
                vs = al_s[(size_t)src*H + h];
                if (EL==2) hv = *(const unsigned*)(hfeat + (size_t)src*M + j);
                else       hv = (unsigned)hfeat[(size_t)src*M + j];
            }
        };
        auto proc = [&](unsigned hv, float vs){
            float vv = vs + ald;
            vv = vv > 0.f ? vv : LEAKY*vv;
            float ex = __expf(vv - mb);
            s += ex;
            acc0 = fmaf(bf2f((u16)hv), ex, acc0);
            if (EL==2) acc1 = fmaf(bf2f((u16)(hv>>16)), ex, acc1);
        };

        unsigned hA0=0,hA1=0,hA2=0,hA3=0, hB0=0,hB1=0,hB2=0,hB3=0;
        float vA0=0,vA1=0,vA2=0,vA3=0, vB0=0,vB1=0,vB2=0,vB3=0;
        int p = p0;
        ld(p, hA0, vA0); ld(p+1, hA1, vA1); ld(p+2, hA2, vA2); ld(p+3, hA3, vA3);
        while (p < p1){
            ld(p+4, hB0, vB0); ld(p+5, hB1, vB1); ld(p+6, hB2, vB2); ld(p+7, hB3, vB3);
            proc(hA0, vA0);
            if (p+1 < p1) proc(hA1, vA1);
            if (p+2 < p1) proc(hA2, vA2);
            if (p+3 < p1) proc(hA3, vA3);
            p += 4;
            if (p >= p1) break;
            ld(p+4, hA0, vA0); ld(p+5, hA1, vA1); ld(p+6, hA2, vA2); ld(p+7, hA3, vA3);
            proc(hB0, vB0);
            if (p+1 < p1) proc(hB1, vB1);
            if (p+2 < p1) proc(hB2, vB2);
            if (p+3 < p1) proc(hB3, vB3);
            p += 4;
        }

        float inv = 1.f/s;                     // s >= e^-40 > 0 (self-loop)
        float o0 = acc0*inv + bj0;
        float o1 = (EL==2) ? acc1*inv + bj1 : 0.f;
        if (STATS){ ls0+=o0; lq0+=o0*o0; ls1+=o1; lq1+=o1*o1; }
        if (!DECODE){
            if (EL==2) *(float2*)(z + (size_t)dst*M + j) = make_float2(o0,o1);
            else       z[(size_t)dst*M + j] = o0;
        } else {
            float a0=o0*w0, a1=o0*w1, a2=o0*w2, a3=o0*w3;
            #pragma unroll
            for (int off=32; off; off>>=1){
                a0 += __shfl_xor(a0, off, 64);
                a1 += __shfl_xor(a1, off, 64);
                a2 += __shfl_xor(a2, off, 64);
                a3 += __shfl_xor(a3, off, 64);
            }
            if (lane == 0){
                float4 o = make_float4(a0+decb[0], a1+decb[1], a2+decb[2], a3+decb[3]);
                *(float4*)(out + (size_t)dst*4) = o;
            }
        }
    }
    if (STATS){
        __shared__ float sls[128], slq[128];
        if (threadIdx.x < 128){ sls[threadIdx.x]=0.f; slq[threadIdx.x]=0.f; }
        __syncthreads();
        atomicAdd(&sls[j], ls0);  atomicAdd(&slq[j], lq0);
        if (EL==2){ atomicAdd(&sls[j+1], ls1); atomicAdd(&slq[j+1], lq1); }
        __syncthreads();
        if (threadIdx.x < 128){
            atomicAdd(cs + threadIdx.x, sls[threadIdx.x]);
            atomicAdd(cq + threadIdx.x, slq[threadIdx.x]);
        }
    }
}

extern "C" void kernel_launch(void* const* d_in, const int* in_sizes, int n_in,
                              void* d_out, int out_size, void* d_ws, size_t ws_size,
                              hipStream_t stream){
    const float* x      = (const float*)d_in[0];
    const int*   ei     = (const int*)  d_in[1];
    const float* enc_W  = (const float*)d_in[2];
    const float* enc_b  = (const float*)d_in[3];
    const float* in_W   = (const float*)d_in[4];
    const float* in_as  = (const float*)d_in[5];
    const float* in_ad  = (const float*)d_in[6];
    const float* in_b   = (const float*)d_in[7];
    const float* hid_W  = (const float*)d_in[8];
    const float* hid_as = (const float*)d_in[9];
    const float* hid_ad = (const float*)d_in[10];
    const float* hid_b  = (const float*)d_in[11];
    const float* bn_g   = (const float*)d_in[12];
    const float* bn_b   = (const float*)d_in[13];
    const float* out_W  = (const float*)d_in[14];
    const float* out_as = (const float*)d_in[15];
    const float* out_ad = (const float*)d_in[16];
    const float* out_b  = (const float*)d_in[17];
    const float* dec_W  = (const float*)d_in[18];
    const float* dec_b  = (const float*)d_in[19];

    const int N = in_sizes[0] / 7;
    const int E = in_sizes[1] / 2;
    const int NB = (N + 1023) / 1024;
    const int NT = (N + 63) / 64;
    const int AGG_BLOCKS = 2048, TOT_WAVES = AGG_BLOCKS*4;

    // workspace layout:
    float*    bufZ   = (float*)d_ws;                  // [N,128] fp32 activations
    float*    al_s   = bufZ + (size_t)N*128;          // [N,4]
    float*    al_d   = al_s + (size_t)N*4;            // [N,4]
    float*    cs     = al_d + (size_t)N*4;            // [128]
    float*    cq     = cs + 128;                      // [128]
    float*    mh     = cq + 128;                      // [8] per-head logit max
    float*    pm     = mh + 8;                        // [256] partial maxes
    float*    scale  = pm + 256;                      // [128]
    float*    shift  = scale + 128;                   // [128]
    int*      deg    = (int*)(shift + 128);           // [N]
    int*      excl   = deg + N;                       // [N]
    int*      rowptr = excl + N;                      // [N+1]
    int*      cursor = rowptr + (N+1);                // [N]
    int*      bsum   = cursor + N;                    // [NB]
    int*      csr    = bsum + NB;                     // [E]
    u16*      hb     = (u16*)(((uintptr_t)(csr + E) + 15) & ~(uintptr_t)15); // [N,128] bf16
    u16*      wk     = hb + (size_t)N*128;
    u16* wk_in_hi  = wk;                    u16* wk_in_lo  = wk_in_hi  + 64*128;
    u16* wk_h0_hi  = wk_in_lo  + 64*128;    u16* wk_h0_lo  = wk_h0_hi  + 128*128;
    u16* wk_h1_hi  = wk_h0_lo  + 128*128;   u16* wk_h1_lo  = wk_h1_hi  + 128*128;
    u16* wk_out_hi = wk_h1_lo  + 128*128;   u16* wk_out_lo = wk_out_hi + 128*64;

    // ---- pack weights ----
    k_pack_w<64,128><<<(64*128+255)/256, 256, 0, stream>>>(in_W, wk_in_hi, wk_in_lo);
    k_pack_w<128,128><<<(128*128+255)/256, 256, 0, stream>>>(hid_W, wk_h0_hi, wk_h0_lo);
    k_pack_w<128,128><<<(128*128+255)/256, 256, 0, stream>>>(hid_W + 128*128, wk_h1_hi, wk_h1_lo);
    k_pack_w<128,64><<<(128*64+255)/256, 256, 0, stream>>>(out_W, wk_out_hi, wk_out_lo);

    // ---- CSR build ----
    hipMemsetAsync(deg, 0, (size_t)N*sizeof(int), stream);
    k_deg   <<<(E+255)/256, 256, 0, stream>>>(ei, E, deg);
    k_scan1 <<<NB, 1024, 0, stream>>>(deg, excl, bsum, N);
    k_scan2 <<<1, 64, 0, stream>>>(bsum, NB);
    k_scan3 <<<(N+1+255)/256, 256, 0, stream>>>(excl, bsum, rowptr, cursor, N, E);
    k_bucket<<<(E+255)/256, 256, 0, stream>>>(ei, E, cursor, csr);

    // ---- encoder ----
    k_encoder<<<(N*64+255)/256, 256, 0, stream>>>(x, enc_W, enc_b, bufZ, N);

    const float invN = 1.f/(float)N;

    // ---- GAT layer 1 (K=64, no input BN) ----
    hipMemsetAsync(cs, 0, 256*sizeof(float), stream);
    k_gemm<64,128,2,2,2,4,4,false><<<NT, 256, 0, stream>>>(bufZ, wk_in_hi, wk_in_lo,
            nullptr, nullptr, in_as, in_ad, hb, al_s, al_d, N);
    k_mh1<4><<<64, 256, 0, stream>>>(al_s, pm, N*4);
    k_mh2<4><<<1, 64, 0, stream>>>(pm, mh);
    k_gat_agg<4,32,true,false><<<AGG_BLOCKS, 256, 0, stream>>>(rowptr, csr, al_s, al_d, mh,
            hb, in_b, bufZ, cs, cq, nullptr, nullptr, nullptr, N, TOT_WAVES);
    k_bn_coef<<<1, 128, 0, stream>>>(cs, cq, bn_g, bn_b, scale, shift, invN);

    // ---- hidden GAT layers (input BN+ReLU fused into GEMM staging) ----
    for (int i = 0; i < 2; i++){
        const u16* whi = i ? wk_h1_hi : wk_h0_hi;
        const u16* wlo = i ? wk_h1_lo : wk_h0_lo;
        hipMemsetAsync(cs, 0, 256*sizeof(float), stream);
        k_gemm<128,128,2,2,2,4,4,true><<<NT, 256, 0, stream>>>(bufZ, whi, wlo,
                scale, shift, hid_as + (size_t)i*128, hid_ad + (size_t)i*128,
                hb, al_s, al_d, N);
        k_mh1<4><<<64, 256, 0, stream>>>(al_s, pm, N*4);
        k_mh2<4><<<1, 64, 0, stream>>>(pm, mh);
        k_gat_agg<4,32,true,false><<<AGG_BLOCKS, 256, 0, stream>>>(rowptr, csr, al_s, al_d, mh,
                hb, hid_b + (size_t)i*128, bufZ, cs, cq, nullptr, nullptr, nullptr, N, TOT_WAVES);
        k_bn_coef<<<1, 128, 0, stream>>>(cs, cq, bn_g + (i+1)*128, bn_b + (i+1)*128, scale, shift, invN);
    }

    // ---- out GAT layer (K=128 -> 1x64) + fused decoder ----
    k_gemm<128,64,4,1,1,4,1,true><<<NT, 256, 0, stream>>>(bufZ, wk_out_hi, wk_out_lo,
            scale, shift, out_as, out_ad, hb, al_s, al_d, N);
    k_mh1<1><<<64, 256, 0, stream>>>(al_s, pm, N);
    k_mh2<1><<<1, 64, 0, stream>>>(pm, mh);
    k_gat_agg<1,64,false,true><<<AGG_BLOCKS, 256, 0, stream>>>(rowptr, csr, al_s, al_d, mh,
            hb, out_b, nullptr, nullptr, nullptr, dec_W, dec_b, (float*)d_out, N, TOT_WAVES);
}

// Round 9
// 925.488 us; speedup vs baseline: 1.6657x; 1.0582x over previous
//
#include <hip/hip_runtime.h>
#include <math.h>

#define LEAKY 0.2f
#define BN_EPS 1e-5f

typedef unsigned short u16;
typedef __bf16 bf16x8 __attribute__((ext_vector_type(8)));
typedef float f32x4 __attribute__((ext_vector_type(4)));
typedef u16 ushort8 __attribute__((ext_vector_type(8)));

__device__ __forceinline__ u16 f2bf(float x){
    unsigned u = __float_as_uint(x);
    u += 0x7FFFu + ((u >> 16) & 1u);          // RNE (finite data, no NaN)
    return (u16)(u >> 16);
}
__device__ __forceinline__ float bf2f(u16 b){ return __uint_as_float(((unsigned)b) << 16); }

// ---------------- encoder ----------------

__global__ __launch_bounds__(256) void k_encoder(const float* __restrict__ x,
        const float* __restrict__ W, const float* __restrict__ b,
        float* __restrict__ z, int N){
    int gid = blockIdx.x*256 + threadIdx.x;
    int n = gid >> 6, j = gid & 63;
    if (n >= N) return;
    float acc = b[j];
    #pragma unroll
    for (int k=0;k<7;k++) acc += x[n*7+k]*W[k*64+j];
    z[(size_t)n*64+j] = acc;
}

// pack W[K][M] fp32 -> hi/lo bf16 in MFMA B-fragment layout
template<int K, int M>
__global__ __launch_bounds__(256) void k_pack_w(const float* __restrict__ W,
        u16* __restrict__ hi, u16* __restrict__ lo){
    int idx = blockIdx.x*256 + threadIdx.x;
    if (idx >= K*M) return;
    int e = idx & 7, l16 = (idx >> 3) & 3, rest = idx >> 5;
    int n = rest % M, t = rest / M;
    int k = t*32 + l16*8 + e;
    float w = W[(size_t)k*M + n];
    u16 hb = f2bf(w);
    hi[idx] = hb;
    lo[idx] = f2bf(w - bf2f(hb));
}

// BN coefs: scale = gamma*rsqrt(var+eps); shift = beta - mu*scale
__global__ void k_bn_coef(const float* __restrict__ cs, const float* __restrict__ cq,
        const float* __restrict__ g, const float* __restrict__ be,
        float* __restrict__ scale, float* __restrict__ shift, float invN){
    int j = threadIdx.x;   // 128
    float mu = cs[j]*invN;
    float var = cq[j]*invN - mu*mu;
    float s = g[j]*rsqrtf(var + BN_EPS);
    scale[j] = s; shift[j] = be[j] - mu*s;
}

// ---------------- per-head global max of al_s (two-pass, no atomics) ----------------

template<int H>
__global__ __launch_bounds__(256) void k_mh1(const float* __restrict__ al,
        float* __restrict__ pm, int total){
    int t = threadIdx.x;
    float m = -1e30f;
    for (int i = blockIdx.x*256 + t; i < total; i += 64*256)
        m = fmaxf(m, al[i]);
    #pragma unroll
    for (int off = H; off < 64; off <<= 1)
        m = fmaxf(m, __shfl_xor(m, off, 64));
    __shared__ float ws[16];
    int lane = t & 63, wid = t >> 6;
    if (lane < H) ws[wid*H + lane] = m;
    __syncthreads();
    if (t < H){
        float mm = ws[t];
        #pragma unroll
        for (int w = 1; w < 4; w++) mm = fmaxf(mm, ws[w*H + t]);
        pm[blockIdx.x*H + t] = mm;
    }
}

template<int H>
__global__ void k_mh2(const float* __restrict__ pm, float* __restrict__ mh){
    int t = threadIdx.x;   // 64 threads
    float m = -1e30f;
    #pragma unroll
    for (int k = 0; k < H; k++) m = fmaxf(m, pm[t + k*64]);
    #pragma unroll
    for (int off = H; off < 64; off <<= 1)
        m = fmaxf(m, __shfl_xor(m, off, 64));
    if (t < H) mh[t] = m;
}

// split-bf16 MFMA GEMM, fused input-BN+ReLU (staging), fused attention-logit
// epilogue; writes h as bf16. (No atomics anywhere.)
template<int K, int M, int RW, int CW, int WR, int WC, int H, bool BNIN>
__global__ __launch_bounds__(256) void k_gemm(const float* __restrict__ z,
        const u16* __restrict__ Whi, const u16* __restrict__ Wlo,
        const float* __restrict__ bnscale, const float* __restrict__ bnshift,
        const float* __restrict__ a_src, const float* __restrict__ a_dst,
        u16* __restrict__ hout, float* __restrict__ al_s, float* __restrict__ al_d,
        int N)
{
    static_assert(RW*CW == 4 && RW*WR*16 == 64 && CW*WC*16 == M, "tile config");
    constexpr int KS = K/32;
    constexpr int KG = K/8;
    __shared__ __align__(16) u16 Ahi[64*K];
    __shared__ __align__(16) u16 Alo[64*K];
    const int brow = blockIdx.x*64;
    const int tid = threadIdx.x;

    for (int u = tid; u < 64*KG; u += 256){
        int row = u / KG, kg = u % KG;
        int gr = brow + row;
        float v[8];
        if (gr < N){
            const float4* p = (const float4*)(z + (size_t)gr*K + kg*8);
            float4 a = p[0], bq = p[1];
            v[0]=a.x; v[1]=a.y; v[2]=a.z; v[3]=a.w;
            v[4]=bq.x; v[5]=bq.y; v[6]=bq.z; v[7]=bq.w;
            if (BNIN){
                const float4* sc = (const float4*)(bnscale + kg*8);
                const float4* sh = (const float4*)(bnshift + kg*8);
                float4 s0=sc[0], s1=sc[1], t0=sh[0], t1=sh[1];
                v[0]=fmaxf(fmaf(v[0],s0.x,t0.x),0.f);
                v[1]=fmaxf(fmaf(v[1],s0.y,t0.y),0.f);
                v[2]=fmaxf(fmaf(v[2],s0.z,t0.z),0.f);
                v[3]=fmaxf(fmaf(v[3],s0.w,t0.w),0.f);
                v[4]=fmaxf(fmaf(v[4],s1.x,t1.x),0.f);
                v[5]=fmaxf(fmaf(v[5],s1.y,t1.y),0.f);
                v[6]=fmaxf(fmaf(v[6],s1.z,t1.z),0.f);
                v[7]=fmaxf(fmaf(v[7],s1.w,t1.w),0.f);
            }
        } else {
            #pragma unroll
            for (int e=0;e<8;e++) v[e]=0.f;
        }
        ushort8 h8, l8;
        #pragma unroll
        for (int e=0;e<8;e++){
            u16 hb = f2bf(v[e]);
            h8[e] = hb;
            l8[e] = f2bf(v[e] - bf2f(hb));
        }
        int rb = row >> 4, t = kg >> 2, lg = kg & 3;
        int base = (((rb*KS + t)*64) + (row & 15) + 16*lg)*8;
        *(ushort8*)&Ahi[base] = h8;
        *(ushort8*)&Alo[base] = l8;
    }
    __syncthreads();

    const int wave = tid >> 6, lane = tid & 63;
    const int wrow = wave / CW, wcol = wave % CW;
    const int l15 = lane & 15, l16 = lane >> 4;

    f32x4 acc[WR][WC];
    #pragma unroll
    for (int r=0;r<WR;r++)
        #pragma unroll
        for (int c=0;c<WC;c++) acc[r][c] = (f32x4){0.f,0.f,0.f,0.f};

    #pragma unroll
    for (int t = 0; t < KS; ++t){
        bf16x8 ah[WR], al[WR];
        #pragma unroll
        for (int r=0;r<WR;r++){
            int rb = wrow*WR + r;
            int off = ((rb*KS + t)*64 + lane)*8;
            ah[r] = *(const bf16x8*)&Ahi[off];
            al[r] = *(const bf16x8*)&Alo[off];
        }
        bf16x8 bh[WC], bl[WC];
        #pragma unroll
        for (int c=0;c<WC;c++){
            int n = (wcol*WC + c)*16 + l15;
            size_t off = ((size_t)(t*M + n)*4 + (size_t)l16)*8;
            bh[c] = *(const bf16x8*)&Whi[off];
            bl[c] = *(const bf16x8*)&Wlo[off];
        }
        #pragma unroll
        for (int r=0;r<WR;r++)
            #pragma unroll
            for (int c=0;c<WC;c++){
                acc[r][c] = __builtin_amdgcn_mfma_f32_16x16x32_bf16(al[r], bh[c], acc[r][c], 0,0,0);
                acc[r][c] = __builtin_amdgcn_mfma_f32_16x16x32_bf16(ah[r], bl[c], acc[r][c], 0,0,0);
                acc[r][c] = __builtin_amdgcn_mfma_f32_16x16x32_bf16(ah[r], bh[c], acc[r][c], 0,0,0);
            }
    }

    // fused attention-logit epilogue
    float as_[WC], ad_[WC];
    #pragma unroll
    for (int c=0;c<WC;c++){
        int colg = (wcol*WC + c)*16 + l15;
        as_[c] = a_src[colg]; ad_[c] = a_dst[colg];
    }
    #pragma unroll
    for (int r=0;r<WR;r++){
        #pragma unroll
        for (int q=0;q<4;q++){
            int rowg = brow + (wrow*WR + r)*16 + l16*4 + q;
            float s0=0.f,d0=0.f,s1=0.f,d1=0.f;
            #pragma unroll
            for (int c=0;c<WC;c++){
                float av = acc[r][c][q];
                if (H==1 || c < WC/2){ s0 += av*as_[c]; d0 += av*ad_[c]; }
                else                 { s1 += av*as_[c]; d1 += av*ad_[c]; }
            }
            #pragma unroll
            for (int off=1; off<16; off<<=1){
                s0 += __shfl_xor(s0, off, 64); d0 += __shfl_xor(d0, off, 64);
                if (H==4){ s1 += __shfl_xor(s1, off, 64); d1 += __shfl_xor(d1, off, 64); }
            }
            if (l15 == 0 && rowg < N){
                if (H==4){
                    al_s[(size_t)rowg*4 + wcol*2]     = s0;
                    al_s[(size_t)rowg*4 + wcol*2 + 1] = s1;
                    al_d[(size_t)rowg*4 + wcol*2]     = d0;
                    al_d[(size_t)rowg*4 + wcol*2 + 1] = d1;
                } else {
                    al_s[rowg] = s0; al_d[rowg] = d0;
                }
            }
        }
    }

    // h write (bf16)
    #pragma unroll
    for (int r=0;r<WR;r++)
        #pragma unroll
        for (int c=0;c<WC;c++){
            int colg = (wcol*WC + c)*16 + l15;
            #pragma unroll
            for (int q=0;q<4;q++){
                int rowg = brow + (wrow*WR + r)*16 + l16*4 + q;
                if (rowg < N) hout[(size_t)rowg*M + colg] = f2bf(acc[r][c][q]);
            }
        }
}

// ---------------- CSR build (once per call) ----------------

__global__ __launch_bounds__(256) void k_deg(const int* __restrict__ ei, int E,
        int* __restrict__ deg){
    int e = blockIdx.x*256 + threadIdx.x;
    if (e < E) atomicAdd(deg + ei[E+e], 1);
}

__device__ __forceinline__ int wave_scan(int v, int lane){
    #pragma unroll
    for (int off=1; off<64; off<<=1){
        int t = __shfl_up(v, off, 64);
        if (lane >= off) v += t;
    }
    return v;
}

__global__ __launch_bounds__(1024) void k_scan1(const int* __restrict__ deg,
        int* __restrict__ excl, int* __restrict__ bsum, int N){
    __shared__ int ws[16];
    int i = blockIdx.x*1024 + threadIdx.x;
    int lane = threadIdx.x & 63, wid = threadIdx.x >> 6;
    int v = (i < N) ? deg[i] : 0;
    int inc = wave_scan(v, lane);
    if (lane == 63) ws[wid] = inc;
    __syncthreads();
    if (wid == 0){
        int wv = (lane < 16) ? ws[lane] : 0;
        int winc = wave_scan(wv, lane);
        if (lane < 16) ws[lane] = winc - wv;
    }
    __syncthreads();
    int off = ws[wid];
    if (i < N) excl[i] = off + inc - v;
    if (threadIdx.x == 1023) bsum[blockIdx.x] = off + inc;
}

__global__ void k_scan2(int* __restrict__ bsum, int nb){
    if (threadIdx.x == 0 && blockIdx.x == 0){
        int c = 0;
        for (int i = 0; i < nb; i++){ int t = bsum[i]; bsum[i] = c; c += t; }
    }
}

__global__ __launch_bounds__(256) void k_scan3(const int* __restrict__ excl,
        const int* __restrict__ bsum, int* __restrict__ rowptr,
        int* __restrict__ cursor, int N, int E){
    int i = blockIdx.x*256 + threadIdx.x;
    if (i < N){
        int r = excl[i] + bsum[i >> 10];
        rowptr[i] = r; cursor[i] = r;
    } else if (i == N){
        rowptr[N] = E;
    }
}

__global__ __launch_bounds__(256) void k_bucket(const int* __restrict__ ei, int E,
        int* __restrict__ cursor, int* __restrict__ csr){
    int e = blockIdx.x*256 + threadIdx.x;
    if (e >= E) return;
    int pos = atomicAdd(cursor + ei[E+e], 1);
    csr[pos] = ei[e];
}

// ---------------- GAT aggregation: lane-group edge parallelism ----------------
// Lane l covers 8 cols (q*8..) of edge group g; one dwordx4 fetches EPS edges'
// rows per instruction; exp chain once per slot; fixed-upper-bound softmax;
// group-reduce per dst. Fused BN stats / decoder.

template<int H, int C, bool STATS, bool DECODE>
__global__ __launch_bounds__(256) void k_gat_agg(
        const int* __restrict__ rowptr, const int* __restrict__ csr_src,
        const float* __restrict__ al_s, const float* __restrict__ al_d,
        const float* __restrict__ mh,
        const u16* __restrict__ hfeat, const float* __restrict__ b,
        float* __restrict__ z, float* __restrict__ cs, float* __restrict__ cq,
        const float* __restrict__ decW, const float* __restrict__ decb,
        float* __restrict__ out, int N, int totWaves)
{
    constexpr int M = H*C;
    constexpr int GS = M/8;        // lanes per edge (16 for M=128, 8 for M=64)
    constexpr int EPS = 64/GS;     // edges per slot == number of groups
    const int lane = threadIdx.x & 63;
    const int q = lane % GS;       // col-block index
    const int g = lane / GS;       // edge group
    const int col0 = q*8;
    const int hd = col0 / C;       // head (8 cols within one head; 8|C)
    const int gw = blockIdx.x*4 + (threadIdx.x >> 6);

    const float mhf = mh[hd];
    float bj[8];
    #pragma unroll
    for (int j=0;j<8;j++) bj[j] = b[col0+j];

    float w[8][4];
    if (DECODE){
        #pragma unroll
        for (int j=0;j<8;j++)
            #pragma unroll
            for (int o=0;o<4;o++) w[j][o] = decW[(col0+j)*4 + o];
    }
    float ls[8], lq[8];
    if (STATS){
        #pragma unroll
        for (int j=0;j<8;j++){ ls[j]=0.f; lq[j]=0.f; }
    }

    for (int dst = gw; dst < N; dst += totWaves){
        int p0 = rowptr[dst], p1 = rowptr[dst+1];     // issue early
        float ald = al_d[(size_t)dst*H + hd];
        float v0 = al_s[(size_t)dst*H + hd] + ald;
        v0 = v0 > 0.f ? v0 : LEAKY*v0;
        float tt = mhf + ald;
        float mb = tt > 0.f ? tt : LEAKY*tt;          // >= segment max
        mb = fminf(mb, v0 + 40.f);                    // keep s in normal range

        float ex0 = __expf(v0 - mb) * (1.0f/EPS);     // split self-loop across groups
        float s = ex0;
        float acc[8];
        ushort8 hd8 = *(const ushort8*)(hfeat + (size_t)dst*M + col0);
        #pragma unroll
        for (int j=0;j<8;j++) acc[j] = bf2f(hd8[j]) * ex0;

        auto LD = [&](int base, ushort8& hv, float& vs){
            int idx = base + g;
            int src = dst;
            if (idx < p1) src = csr_src[idx];         // predicated, in-bounds
            float t = al_s[(size_t)src*H + hd];
            vs = (idx < p1) ? t : -1e30f;             // masked-out -> ex = 0
            hv = *(const ushort8*)(hfeat + (size_t)src*M + col0);
        };
        auto PR = [&](const ushort8& hv, float vs){
            float vv = vs + ald;
            vv = vv > 0.f ? vv : LEAKY*vv;
            float ex = __expf(vv - mb);
            s += ex;
            #pragma unroll
            for (int j=0;j<8;j++) acc[j] = fmaf(bf2f(hv[j]), ex, acc[j]);
        };

        ushort8 hvA, hvB; float vsA=0.f, vsB=0.f;
        int p = p0;
        LD(p, hvA, vsA);
        while (p < p1){
            LD(p+EPS, hvB, vsB);
            PR(hvA, vsA);
            p += EPS;
            if (p >= p1) break;
            LD(p+EPS, hvA, vsA);
            PR(hvB, vsB);
            p += EPS;
        }

        // reduce across edge groups (lanes differing by multiples of GS)
        #pragma unroll
        for (int off = GS; off < 64; off <<= 1){
            s += __shfl_xor(s, off, 64);
            #pragma unroll
            for (int j=0;j<8;j++) acc[j] += __shfl_xor(acc[j], off, 64);
        }
        float inv = 1.f/s;
        float o8[8];
        #pragma unroll
        for (int j=0;j<8;j++) o8[j] = acc[j]*inv + bj[j];

        if (STATS){
            #pragma unroll
            for (int j=0;j<8;j++){ ls[j] += o8[j]; lq[j] += o8[j]*o8[j]; }
        }
        if (!DECODE){
            if (lane < GS){
                float4 w0 = make_float4(o8[0],o8[1],o8[2],o8[3]);
                float4 w1 = make_float4(o8[4],o8[5],o8[6],o8[7]);
                *(float4*)(z + (size_t)dst*M + col0)     = w0;
                *(float4*)(z + (size_t)dst*M + col0 + 4) = w1;
            }
        } else {
            float p4[4] = {0.f,0.f,0.f,0.f};
            #pragma unroll
            for (int j=0;j<8;j++)
                #pragma unroll
                for (int o=0;o<4;o++) p4[o] = fmaf(o8[j], w[j][o], p4[o]);
            #pragma unroll
            for (int off=1; off<GS; off<<=1){
                #pragma unroll
                for (int o=0;o<4;o++) p4[o] += __shfl_xor(p4[o], off, 64);
            }
            if (lane == 0){
                float4 o = make_float4(p4[0]+decb[0], p4[1]+decb[1],
                                       p4[2]+decb[2], p4[3]+decb[3]);
                *(float4*)(out + (size_t)dst*4) = o;
            }
        }
    }

    if (STATS){
        __shared__ float sls[128], slq[128];
        if (threadIdx.x < 128){ sls[threadIdx.x]=0.f; slq[threadIdx.x]=0.f; }
        __syncthreads();
        if (lane < GS){      // one copy per wave (stats identical across groups)
            #pragma unroll
            for (int j=0;j<8;j++){
                atomicAdd(&sls[col0+j], ls[j]);
                atomicAdd(&slq[col0+j], lq[j]);
            }
        }
        __syncthreads();
        if (threadIdx.x < 128){
            atomicAdd(cs + threadIdx.x, sls[threadIdx.x]);
            atomicAdd(cq + threadIdx.x, slq[threadIdx.x]);
        }
    }
}

extern "C" void kernel_launch(void* const* d_in, const int* in_sizes, int n_in,
                              void* d_out, int out_size, void* d_ws, size_t ws_size,
                              hipStream_t stream){
    const float* x      = (const float*)d_in[0];
    const int*   ei     = (const int*)  d_in[1];
    const float* enc_W  = (const float*)d_in[2];
    const float* enc_b  = (const float*)d_in[3];
    const float* in_W   = (const float*)d_in[4];
    const float* in_as  = (const float*)d_in[5];
    const float* in_ad  = (const float*)d_in[6];
    const float* in_b   = (const float*)d_in[7];
    const float* hid_W  = (const float*)d_in[8];
    const float* hid_as = (const float*)d_in[9];
    const float* hid_ad = (const float*)d_in[10];
    const float* hid_b  = (const float*)d_in[11];
    const float* bn_g   = (const float*)d_in[12];
    const float* bn_b   = (const float*)d_in[13];
    const float* out_W  = (const float*)d_in[14];
    const float* out_as = (const float*)d_in[15];
    const float* out_ad = (const float*)d_in[16];
    const float* out_b  = (const float*)d_in[17];
    const float* dec_W  = (const float*)d_in[18];
    const float* dec_b  = (const float*)d_in[19];

    const int N = in_sizes[0] / 7;
    const int E = in_sizes[1] / 2;
    const int NB = (N + 1023) / 1024;
    const int NT = (N + 63) / 64;
    const int AGG_BLOCKS = 2048, TOT_WAVES = AGG_BLOCKS*4;

    // workspace layout:
    float*    bufZ   = (float*)d_ws;                  // [N,128] fp32 activations
    float*    al_s   = bufZ + (size_t)N*128;          // [N,4]
    float*    al_d   = al_s + (size_t)N*4;            // [N,4]
    float*    cs     = al_d + (size_t)N*4;            // [128]
    float*    cq     = cs + 128;                      // [128]
    float*    mh     = cq + 128;                      // [8] per-head logit max
    float*    pm     = mh + 8;                        // [256] partial maxes
    float*    scale  = pm + 256;                      // [128]
    float*    shift  = scale + 128;                   // [128]
    int*      deg    = (int*)(shift + 128);           // [N]
    int*      excl   = deg + N;                       // [N]
    int*      rowptr = excl + N;                      // [N+1]
    int*      cursor = rowptr + (N+1);                // [N]
    int*      bsum   = cursor + N;                    // [NB]
    int*      csr    = bsum + NB;                     // [E]
    u16*      hb     = (u16*)(((uintptr_t)(csr + E) + 15) & ~(uintptr_t)15); // [N,128] bf16
    u16*      wk     = hb + (size_t)N*128;
    u16* wk_in_hi  = wk;                    u16* wk_in_lo  = wk_in_hi  + 64*128;
    u16* wk_h0_hi  = wk_in_lo  + 64*128;    u16* wk_h0_lo  = wk_h0_hi  + 128*128;
    u16* wk_h1_hi  = wk_h0_lo  + 128*128;   u16* wk_h1_lo  = wk_h1_hi  + 128*128;
    u16* wk_out_hi = wk_h1_lo  + 128*128;   u16* wk_out_lo = wk_out_hi + 128*64;

    // ---- pack weights ----
    k_pack_w<64,128><<<(64*128+255)/256, 256, 0, stream>>>(in_W, wk_in_hi, wk_in_lo);
    k_pack_w<128,128><<<(128*128+255)/256, 256, 0, stream>>>(hid_W, wk_h0_hi, wk_h0_lo);
    k_pack_w<128,128><<<(128*128+255)/256, 256, 0, stream>>>(hid_W + 128*128, wk_h1_hi, wk_h1_lo);
    k_pack_w<128,64><<<(128*64+255)/256, 256, 0, stream>>>(out_W, wk_out_hi, wk_out_lo);

    // ---- CSR build ----
    hipMemsetAsync(deg, 0, (size_t)N*sizeof(int), stream);
    k_deg   <<<(E+255)/256, 256, 0, stream>>>(ei, E, deg);
    k_scan1 <<<NB, 1024, 0, stream>>>(deg, excl, bsum, N);
    k_scan2 <<<1, 64, 0, stream>>>(bsum, NB);
    k_scan3 <<<(N+1+255)/256, 256, 0, stream>>>(excl, bsum, rowptr, cursor, N, E);
    k_bucket<<<(E+255)/256, 256, 0, stream>>>(ei, E, cursor, csr);

    // ---- encoder ----
    k_encoder<<<(N*64+255)/256, 256, 0, stream>>>(x, enc_W, enc_b, bufZ, N);

    const float invN = 1.f/(float)N;

    // ---- GAT layer 1 (K=64, no input BN) ----
    hipMemsetAsync(cs, 0, 256*sizeof(float), stream);
    k_gemm<64,128,2,2,2,4,4,false><<<NT, 256, 0, stream>>>(bufZ, wk_in_hi, wk_in_lo,
            nullptr, nullptr, in_as, in_ad, hb, al_s, al_d, N);
    k_mh1<4><<<64, 256, 0, stream>>>(al_s, pm, N*4);
    k_mh2<4><<<1, 64, 0, stream>>>(pm, mh);
    k_gat_agg<4,32,true,false><<<AGG_BLOCKS, 256, 0, stream>>>(rowptr, csr, al_s, al_d, mh,
            hb, in_b, bufZ, cs, cq, nullptr, nullptr, nullptr, N, TOT_WAVES);
    k_bn_coef<<<1, 128, 0, stream>>>(cs, cq, bn_g, bn_b, scale, shift, invN);

    // ---- hidden GAT layers (input BN+ReLU fused into GEMM staging) ----
    for (int i = 0; i < 2; i++){
        const u16* whi = i ? wk_h1_hi : wk_h0_hi;
        const u16* wlo = i ? wk_h1_lo : wk_h0_lo;
        hipMemsetAsync(cs, 0, 256*sizeof(float), stream);
        k_gemm<128,128,2,2,2,4,4,true><<<NT, 256, 0, stream>>>(bufZ, whi, wlo,
                scale, shift, hid_as + (size_t)i*128, hid_ad + (size_t)i*128,
                hb, al_s, al_d, N);
        k_mh1<4><<<64, 256, 0, stream>>>(al_s, pm, N*4);
        k_mh2<4><<<1, 64, 0, stream>>>(pm, mh);
        k_gat_agg<4,32,true,false><<<AGG_BLOCKS, 256, 0, stream>>>(rowptr, csr, al_s, al_d, mh,
                hb, hid_b + (size_t)i*128, bufZ, cs, cq, nullptr, nullptr, nullptr, N, TOT_WAVES);
        k_bn_coef<<<1, 128, 0, stream>>>(cs, cq, bn_g + (i+1)*128, bn_b + (i+1)*128, scale, shift, invN);
    }

    // ---- out GAT layer (K=128 -> 1x64) + fused decoder ----
    k_gemm<128,64,4,1,1,4,1,true><<<NT, 256, 0, stream>>>(bufZ, wk_out_hi, wk_out_lo,
            scale, shift, out_as, out_ad, hb, al_s, al_d, N);
    k_mh1<1><<<64, 256, 0, stream>>>(al_s, pm, N);
    k_mh2<1><<<1, 64, 0, stream>>>(pm, mh);
    k_gat_agg<1,64,false,true><<<AGG_BLOCKS, 256, 0, stream>>>(rowptr, csr, al_s, al_d, mh,
            hb, out_b, nullptr, nullptr, nullptr, dec_W, dec_b, (float*)d_out, N, TOT_WAVES);
}